// Round 8
// baseline (523.870 us; speedup 1.0000x reference)
//
#include <hip/hip_runtime.h>
#include <math.h>

#define B_ 2
#define N_ 2048
#define C_ 1024
#define H_ 16
#define D_ 64

typedef __attribute__((ext_vector_type(8))) short short8v;
typedef __attribute__((ext_vector_type(4))) short short4v;
typedef __attribute__((ext_vector_type(4))) float f32x4;

static __device__ __forceinline__ short f2bf(float f) {
    union { float f; unsigned u; } v; v.f = f;
    unsigned r = v.u + 0x7FFFu + ((v.u >> 16) & 1u);   // RNE
    return (short)(r >> 16);
}

// Split fp32 into hi/lo truncated bf16: f = hi + lo + O(2^-16 * f).
// a*b ~= ah*bh + ah*bl + al*bh  (dropped al*bl ~ 2^-16 rel) -> fp32-grade GEMM.
static __device__ __forceinline__ void splitbf(float f, short& h, short& l) {
    union { float f; unsigned u; } v; v.f = f;
    const unsigned uh = v.u & 0xFFFF0000u;
    h = (short)(uh >> 16);
    union { unsigned u; float f; } w; w.u = uh;
    union { float f; unsigned u; } x; x.f = f - w.f;   // exact (Sterbenz)
    l = (short)(x.u >> 16);
}

// ---------------------------------------------------------------------------
// split_a: elementwise fp32 -> (hi,lo) bf16 arrays. 4 floats/thread.
// ---------------------------------------------------------------------------
__global__ __launch_bounds__(256) void split_a(const float* __restrict__ src,
                                               short* __restrict__ hi,
                                               short* __restrict__ lo) {
    const int i = (blockIdx.x * 256 + threadIdx.x) * 4;
    const float4 f = *(const float4*)&src[i];
    short4v h, l;
    short th_, tl_;
    splitbf(f.x, th_, tl_); h[0] = th_; l[0] = tl_;
    splitbf(f.y, th_, tl_); h[1] = th_; l[1] = tl_;
    splitbf(f.z, th_, tl_); h[2] = th_; l[2] = tl_;
    splitbf(f.w, th_, tl_); h[3] = th_; l[3] = tl_;
    *(short4v*)&hi[i] = h;
    *(short4v*)&lo[i] = l;
}

// ---------------------------------------------------------------------------
// split_wt: W[K][N] fp32 -> Wt_hi/Wt_lo [N][K] bf16 (transpose + split).
// ---------------------------------------------------------------------------
__global__ __launch_bounds__(256) void split_wt(const float* __restrict__ Wm,
                                                short* __restrict__ th,
                                                short* __restrict__ tl,
                                                int K, int N) {
    __shared__ float Ls[64][68];
    const int t  = threadIdx.x;
    const int n0 = blockIdx.x * 64;
    const int k0 = blockIdx.y * 64;
#pragma unroll
    for (int it = 0; it < 4; ++it) {
        const int kl = it * 16 + (t >> 4);
        const int nl = (t & 15) * 4;
        *(float4*)&Ls[kl][nl] = *(const float4*)&Wm[(size_t)(k0 + kl) * N + n0 + nl];
    }
    __syncthreads();
#pragma unroll
    for (int it = 0; it < 4; ++it) {
        const int idx = it * 256 + t;
        const int nl  = idx & 63;
        const int ks  = (idx >> 6) * 4;
        short4v h, l;
#pragma unroll
        for (int j = 0; j < 4; ++j) {
            short th_, tl_;
            splitbf(Ls[ks + j][nl], th_, tl_);
            h[j] = th_; l[j] = tl_;
        }
        *(short4v*)&th[(size_t)(n0 + nl) * K + k0 + ks] = h;
        *(short4v*)&tl[(size_t)(n0 + nl) * K + k0 + ks] = l;
    }
}

// ---------------------------------------------------------------------------
// bf16-input x3 MFMA GEMM: C = A(MxK) @ Bt(NxK)^T, pre-split hi/lo operands.
// 128x128 tile, BK=32, 4 waves (2x2). Unchanged from round 7 (verified).
// ---------------------------------------------------------------------------
#define GKSTR 40

__global__ __launch_bounds__(256) void gemm_bf3(const short* __restrict__ Ah,
                                                const short* __restrict__ Al,
                                                const short* __restrict__ Bth,
                                                const short* __restrict__ Btl,
                                                short* __restrict__ Cm,
                                                int K, int N) {
    __shared__ __align__(16) short Ahs[128][GKSTR];
    __shared__ __align__(16) short Als[128][GKSTR];
    __shared__ __align__(16) short Bhs[128][GKSTR];
    __shared__ __align__(16) short Bls[128][GKSTR];

    const int t  = threadIdx.x;
    const int w  = t >> 6;
    const int lq = t & 15;
    const int hq = (t & 63) >> 4;
    const int wr = w >> 1;                 // wave row (m) 0..1
    const int wc = w & 1;                  // wave col (n) 0..1
    const int m0 = blockIdx.y * 128;
    const int n0 = blockIdx.x * 128;

    const int srow = t >> 1;
    const int scol = (t & 1) * 16;

    const short* gA_h = &Ah[(size_t)(m0 + srow) * K + scol];
    const short* gA_l = &Al[(size_t)(m0 + srow) * K + scol];
    const short* gB_h = &Bth[(size_t)(n0 + srow) * K + scol];
    const short* gB_l = &Btl[(size_t)(n0 + srow) * K + scol];

    f32x4 acc[4][4];
#pragma unroll
    for (int mi = 0; mi < 4; ++mi)
#pragma unroll
        for (int ni = 0; ni < 4; ++ni) acc[mi][ni] = (f32x4){0.f, 0.f, 0.f, 0.f};

    short8v ra_h0 = *(const short8v*)gA_h,       ra_h1 = *(const short8v*)(gA_h + 8);
    short8v ra_l0 = *(const short8v*)gA_l,       ra_l1 = *(const short8v*)(gA_l + 8);
    short8v rb_h0 = *(const short8v*)gB_h,       rb_h1 = *(const short8v*)(gB_h + 8);
    short8v rb_l0 = *(const short8v*)gB_l,       rb_l1 = *(const short8v*)(gB_l + 8);

    for (int k0 = 0; k0 < K; k0 += 32) {
        __syncthreads();
        *(short8v*)&Ahs[srow][scol]     = ra_h0;
        *(short8v*)&Ahs[srow][scol + 8] = ra_h1;
        *(short8v*)&Als[srow][scol]     = ra_l0;
        *(short8v*)&Als[srow][scol + 8] = ra_l1;
        *(short8v*)&Bhs[srow][scol]     = rb_h0;
        *(short8v*)&Bhs[srow][scol + 8] = rb_h1;
        *(short8v*)&Bls[srow][scol]     = rb_l0;
        *(short8v*)&Bls[srow][scol + 8] = rb_l1;
        __syncthreads();

        const int kn = k0 + 32;
        if (kn < K) {
            ra_h0 = *(const short8v*)(gA_h + kn); ra_h1 = *(const short8v*)(gA_h + kn + 8);
            ra_l0 = *(const short8v*)(gA_l + kn); ra_l1 = *(const short8v*)(gA_l + kn + 8);
            rb_h0 = *(const short8v*)(gB_h + kn); rb_h1 = *(const short8v*)(gB_h + kn + 8);
            rb_l0 = *(const short8v*)(gB_l + kn); rb_l1 = *(const short8v*)(gB_l + kn + 8);
        }

        short8v bnh[4], bnl[4];
#pragma unroll
        for (int ni = 0; ni < 4; ++ni) {
            bnh[ni] = *(const short8v*)&Bhs[wc * 64 + ni * 16 + lq][hq * 8];
            bnl[ni] = *(const short8v*)&Bls[wc * 64 + ni * 16 + lq][hq * 8];
        }
#pragma unroll
        for (int mi = 0; mi < 4; ++mi) {
            const short8v amh = *(const short8v*)&Ahs[wr * 64 + mi * 16 + lq][hq * 8];
            const short8v aml = *(const short8v*)&Als[wr * 64 + mi * 16 + lq][hq * 8];
#pragma unroll
            for (int ni = 0; ni < 4; ++ni) {
                acc[mi][ni] = __builtin_amdgcn_mfma_f32_16x16x32_bf16(amh, bnh[ni], acc[mi][ni], 0, 0, 0);
                acc[mi][ni] = __builtin_amdgcn_mfma_f32_16x16x32_bf16(amh, bnl[ni], acc[mi][ni], 0, 0, 0);
                acc[mi][ni] = __builtin_amdgcn_mfma_f32_16x16x32_bf16(aml, bnh[ni], acc[mi][ni], 0, 0, 0);
            }
        }
    }

#pragma unroll
    for (int mi = 0; mi < 4; ++mi)
#pragma unroll
        for (int ni = 0; ni < 4; ++ni) {
            const int col = n0 + wc * 64 + ni * 16 + lq;
#pragma unroll
            for (int r = 0; r < 4; ++r) {
                const int row = m0 + wr * 64 + mi * 16 + hq * 4 + r;
                Cm[(size_t)row * N + col] = f2bf(acc[mi][ni][r]);
            }
        }
}

// ---------------------------------------------------------------------------
// Transpose bf16 V (columns C..2C of kv_bf) into Vt_g[b][h][d][j].
// ---------------------------------------------------------------------------
__global__ __launch_bounds__(256) void v_transpose(const short* __restrict__ kv_bf,
                                                   short* __restrict__ vt) {
    __shared__ __align__(16) short Ls[128][72];
    const int t  = threadIdx.x;
    const int jt = blockIdx.x * 128;
    const int h  = blockIdx.y;
    const int b  = blockIdx.z;
    const short* src = kv_bf + (size_t)b * N_ * 2 * C_ + C_ + h * D_;
#pragma unroll
    for (int it = 0; it < 4; ++it) {
        const int idx = it * 256 + t;
        const int j = idx >> 3, d0 = (idx & 7) * 8;
        *(short8v*)&Ls[j][d0] = *(const short8v*)&src[(size_t)(jt + j) * (2 * C_) + d0];
    }
    __syncthreads();
    short* dst = vt + ((size_t)(b * H_ + h)) * D_ * N_;
#pragma unroll
    for (int it = 0; it < 4; ++it) {
        const int idx = it * 256 + t;
        const int d  = idx >> 4;           // 0..63
        const int j0 = (idx & 15) * 8;
        short8v s;
#pragma unroll
        for (int jj = 0; jj < 8; ++jj) s[jj] = Ls[j0 + jj][d];
        *(short8v*)&dst[(size_t)d * N_ + jt + j0] = s;
    }
}

// ---------------------------------------------------------------------------
// BARRIER-FREE two-pass MFMA attention (de-staged, r8).
// With the XCD swizzle each XCD's working set (4 panels x (K 256KB + V^T
// 256KB)) is L2-resident, so K/V/mask fragments are read DIRECTLY from
// global (16B contiguous loads) -- no Ks/Vt LDS, no staging, no prefetch.
// The only LDS (Ps, linv_s) is indexed by wave id => wave-private; the
// compiler's lgkmcnt ordering covers the intra-wave RAW, so the kernel has
// ZERO __syncthreads. LDS 72->35 KB => 3-4 blocks/CU, waves free-run.
// Loop order (j strips ascending; tile/cb/db/kb identical to r7) =>
// bit-identical accumulation => absmax unchanged.
// ---------------------------------------------------------------------------
#define PSTR 136

__global__ __launch_bounds__(256) void attn_mfma(const short* __restrict__ q,
                                                 const short* __restrict__ kv,
                                                 const short* __restrict__ vtg,
                                                 const int* __restrict__ mask,
                                                 float* __restrict__ out_att,
                                                 float* __restrict__ out_w) {
    __shared__ __align__(16) short Ps[4][32][PSTR];      // 34816 B (wave-private)
    __shared__ float linv_s[4][32];                      // wave-private

    const int t  = threadIdx.x;
    const int w  = t >> 6;
    const int l  = t & 63;
    const int lq = l & 15;
    const int hq = l >> 4;

    // XCD-aware bijective swizzle (512 blocks, 8 XCDs, 64 each = 4 panels)
    const int lin = blockIdx.x;
    const int swz = (lin & 7) * 64 + (lin >> 3);
    const int qb = swz & 15;            // 0..15
    const int h  = (swz >> 4) & 15;     // 0..15
    const int b  = swz >> 8;            // 0..1
    const int i0 = qb * 128 + w * 32;   // wave's first q row

    // ---- Q fragments, 2 row-groups: A[m=lq][k=kb*32+hq*8+e] ----
    short8v qa[2][2];
#pragma unroll
    for (int g = 0; g < 2; ++g) {
        const short* qrow = q + ((size_t)(b * N_ + i0 + g * 16 + lq)) * C_ + h * D_;
        qa[g][0] = *(const short8v*)&qrow[hq * 8];
        qa[g][1] = *(const short8v*)&qrow[32 + hq * 8];
    }

    int mr[2][4];
#pragma unroll
    for (int g = 0; g < 2; ++g)
#pragma unroll
        for (int r = 0; r < 4; ++r) mr[g][r] = mask[b * N_ + i0 + g * 16 + hq * 4 + r];

    const short* kbase = kv + (size_t)b * N_ * 2 * C_ + h * D_;
    const short* vtb   = vtg + ((size_t)(b * H_ + h)) * D_ * N_;
    const int*   mbase = mask + b * N_;

    // ---------------- pass 1: row sums (no barriers, no LDS) ----------------
    float lsum[2][4];
#pragma unroll
    for (int g = 0; g < 2; ++g)
#pragma unroll
        for (int r = 0; r < 4; ++r) lsum[g][r] = 0.f;

    for (int cb0 = 0; cb0 < 128; ++cb0) {
        const int j = cb0 * 16 + lq;                 // same strip order as r7
        const short* krow = kbase + (size_t)j * (2 * C_);
        const short8v b0 = *(const short8v*)&krow[hq * 8];
        const short8v b1 = *(const short8v*)&krow[32 + hq * 8];
        const int mc = mbase[j];
#pragma unroll
        for (int g = 0; g < 2; ++g) {
            f32x4 acc = {0.f, 0.f, 0.f, 0.f};
            acc = __builtin_amdgcn_mfma_f32_16x16x32_bf16(qa[g][0], b0, acc, 0, 0, 0);
            acc = __builtin_amdgcn_mfma_f32_16x16x32_bf16(qa[g][1], b1, acc, 0, 0, 0);
#pragma unroll
            for (int r = 0; r < 4; ++r)
                lsum[g][r] += mr[g][r] ? 1.0f : (mc ? 0.0f : __expf(acc[r] * 0.125f));
        }
    }
    float inv[2][4];
#pragma unroll
    for (int g = 0; g < 2; ++g)
#pragma unroll
        for (int r = 0; r < 4; ++r) {
            float s = lsum[g][r];
#pragma unroll
            for (int off = 1; off < 16; off <<= 1) s += __shfl_xor(s, off, 64);
            inv[g][r] = 1.0f / s;
        }
    if (lq == 0)
#pragma unroll
        for (int g = 0; g < 2; ++g)
#pragma unroll
            for (int r = 0; r < 4; ++r) linv_s[w][g * 16 + hq * 4 + r] = inv[g][r];

    float* wbase[2];
#pragma unroll
    for (int g = 0; g < 2; ++g)
        wbase[g] = out_w + ((size_t)((b * H_ + h) * N_ + i0 + g * 16 + hq * 4)) * N_;

    f32x4 oacc[4][2];
#pragma unroll
    for (int db = 0; db < 4; ++db)
#pragma unroll
        for (int g = 0; g < 2; ++g) oacc[db][g] = (f32x4){0.f, 0.f, 0.f, 0.f};

    // ---------------- pass 2 (no barriers; Ps is wave-private) --------------
    for (int tile = 0; tile < 16; ++tile) {
        const int jt = tile * 128;

#pragma unroll
        for (int cb = 0; cb < 8; ++cb) {
            const int jcol = cb * 16 + lq;
            const short* krow = kbase + (size_t)(jt + jcol) * (2 * C_);
            const short8v b0 = *(const short8v*)&krow[hq * 8];
            const short8v b1 = *(const short8v*)&krow[32 + hq * 8];
            const int mc = mbase[jt + jcol];
#pragma unroll
            for (int g = 0; g < 2; ++g) {
                f32x4 acc = {0.f, 0.f, 0.f, 0.f};
                acc = __builtin_amdgcn_mfma_f32_16x16x32_bf16(qa[g][0], b0, acc, 0, 0, 0);
                acc = __builtin_amdgcn_mfma_f32_16x16x32_bf16(qa[g][1], b1, acc, 0, 0, 0);
#pragma unroll
                for (int r = 0; r < 4; ++r) {
                    const float ev = mr[g][r] ? 1.0f : (mc ? 0.0f : __expf(acc[r] * 0.125f));
                    wbase[g][(size_t)r * N_ + jt + jcol] = ev * inv[g][r];   // normalized
                    Ps[w][g * 16 + hq * 4 + r][jcol] = f2bf(ev);
                }
            }
        }
        // intra-wave Ps RAW: compiler-emitted lgkmcnt ordering suffices

        // att^T += V^T @ P  (pb from wave-private LDS, va direct from L2)
        short8v pb[2][4];
#pragma unroll
        for (int kb = 0; kb < 4; ++kb) {
            pb[0][kb] = *(short8v*)&Ps[w][lq][kb * 32 + hq * 8];
            pb[1][kb] = *(short8v*)&Ps[w][16 + lq][kb * 32 + hq * 8];
        }
#pragma unroll
        for (int db = 0; db < 4; ++db)
#pragma unroll
            for (int kb = 0; kb < 4; ++kb) {
                const short8v va = *(const short8v*)&vtb[(size_t)(db * 16 + lq) * N_ + jt + kb * 32 + hq * 8];
                oacc[db][0] = __builtin_amdgcn_mfma_f32_16x16x32_bf16(va, pb[0][kb], oacc[db][0], 0, 0, 0);
                oacc[db][1] = __builtin_amdgcn_mfma_f32_16x16x32_bf16(va, pb[1][kb], oacc[db][1], 0, 0, 0);
            }
    }

    // ---- att: scale accumulators, scalar stores (row=g*16+lq, d=db*16+hq*4+r) ----
#pragma unroll
    for (int g = 0; g < 2; ++g) {
        const float invi = linv_s[w][g * 16 + lq];
        const size_t abase = ((size_t)(b * N_ + i0 + g * 16 + lq)) * C_ + h * D_;
#pragma unroll
        for (int db = 0; db < 4; ++db)
#pragma unroll
            for (int r = 0; r < 4; ++r)
                out_att[abase + db * 16 + hq * 4 + r] = oacc[db][g][r] * invi;
    }
}

// ---------------------------------------------------------------------------
// Workspace layout (shorts), total 24M shorts = 48 MB:
//   qbf  [0,  4M)   q bf16
//   kvbf [4M, 12M)  kv bf16
//   Ah   [12M,16M)  A-split hi (reused); vt overlays after gemms
//   Al   [16M,20M)  A-split lo
//   Wth  [20M,22M)  W^T hi
//   Wtl  [22M,24M)  W^T lo
// ---------------------------------------------------------------------------
extern "C" void kernel_launch(void* const* d_in, const int* in_sizes, int n_in,
                              void* d_out, int out_size, void* d_ws, size_t ws_size,
                              hipStream_t stream) {
    const float* hs   = (const float*)d_in[0];
    const float* ehs  = (const float*)d_in[1];
    const int*   mask = (const int*)d_in[2];
    const float* W_q  = (const float*)d_in[3];
    const float* W_c  = (const float*)d_in[4];

    float* out_att = (float*)d_out;
    float* out_w   = (float*)d_out + (size_t)B_ * N_ * C_;

    const size_t M1 = (size_t)1024 * 1024;
    short* qbf  = (short*)d_ws;
    short* kvbf = qbf + 4 * M1;
    short* Ah   = kvbf + 8 * M1;
    short* Al   = Ah + 4 * M1;
    short* vt   = Ah;                       // overlay: used only after gemms
    short* Wth  = Al + 4 * M1;
    short* Wtl  = Wth + 2 * M1;

    const int nelems_a = B_ * N_ * C_;      // 4M

    // ---- q = hs @ W_q ----
    split_a<<<dim3(nelems_a / 1024), 256, 0, stream>>>(hs, Ah, Al);
    split_wt<<<dim3(C_ / 64, C_ / 64), 256, 0, stream>>>(W_q, Wth, Wtl, C_, C_);
    gemm_bf3<<<dim3(C_ / 128, (B_ * N_) / 128), 256, 0, stream>>>(
        Ah, Al, Wth, Wtl, qbf, C_, C_);

    // ---- kv = ehs @ W_c ----
    split_a<<<dim3(nelems_a / 1024), 256, 0, stream>>>(ehs, Ah, Al);
    split_wt<<<dim3((2 * C_) / 64, C_ / 64), 256, 0, stream>>>(W_c, Wth, Wtl, C_, 2 * C_);
    gemm_bf3<<<dim3((2 * C_) / 128, (B_ * N_) / 128), 256, 0, stream>>>(
        Ah, Al, Wth, Wtl, kvbf, C_, 2 * C_);

    // ---- V transpose + attention ----
    v_transpose<<<dim3(N_ / 128, H_, B_), 256, 0, stream>>>(kvbf, vt);
    attn_mfma<<<dim3(512), 256, 0, stream>>>(
        qbf, kvbf, vt, mask, out_att, out_w);
}

// Round 9
// 328.995 us; speedup vs baseline: 1.5923x; 1.5923x over previous
//
#include <hip/hip_runtime.h>
#include <math.h>

#define B_ 2
#define N_ 2048
#define C_ 1024
#define H_ 16
#define D_ 64

typedef __attribute__((ext_vector_type(8))) short short8v;
typedef __attribute__((ext_vector_type(4))) short short4v;
typedef __attribute__((ext_vector_type(4))) float f32x4;

static __device__ __forceinline__ short f2bf(float f) {
    union { float f; unsigned u; } v; v.f = f;
    unsigned r = v.u + 0x7FFFu + ((v.u >> 16) & 1u);   // RNE
    return (short)(r >> 16);
}

// Split fp32 into hi/lo truncated bf16: f = hi + lo + O(2^-16 * f).
// a*b ~= ah*bh + ah*bl + al*bh  (dropped al*bl ~ 2^-16 rel) -> fp32-grade GEMM.
static __device__ __forceinline__ void splitbf(float f, short& h, short& l) {
    union { float f; unsigned u; } v; v.f = f;
    const unsigned uh = v.u & 0xFFFF0000u;
    h = (short)(uh >> 16);
    union { unsigned u; float f; } w; w.u = uh;
    union { float f; unsigned u; } x; x.f = f - w.f;   // exact (Sterbenz)
    l = (short)(x.u >> 16);
}

// ---------------------------------------------------------------------------
// split_aw: fused {elementwise A-split} + {W transpose-split}.
// Blocks [0, nA)        : A path -- fp32 -> (hi,lo) bf16, 4 floats/thread.
// Blocks [nA, nA+nW)    : W path -- W[K][N] -> Wt_hi/Wt_lo [N][K] via LDS tile.
// Bodies byte-identical to the r7 split_a / split_wt (verified).
// ---------------------------------------------------------------------------
__global__ __launch_bounds__(256) void split_aw(const float* __restrict__ src,
                                                short* __restrict__ hi,
                                                short* __restrict__ lo,
                                                int nA,
                                                const float* __restrict__ Wm,
                                                short* __restrict__ th,
                                                short* __restrict__ tl,
                                                int K, int N) {
    __shared__ float Ls[64][68];
    const int t = threadIdx.x;
    if ((int)blockIdx.x < nA) {
        const int i = (blockIdx.x * 256 + t) * 4;
        const float4 f = *(const float4*)&src[i];
        short4v h, l;
        short th_, tl_;
        splitbf(f.x, th_, tl_); h[0] = th_; l[0] = tl_;
        splitbf(f.y, th_, tl_); h[1] = th_; l[1] = tl_;
        splitbf(f.z, th_, tl_); h[2] = th_; l[2] = tl_;
        splitbf(f.w, th_, tl_); h[3] = th_; l[3] = tl_;
        *(short4v*)&hi[i] = h;
        *(short4v*)&lo[i] = l;
        return;
    }
    // ---- W path ----
    const int wb  = blockIdx.x - nA;
    const int nbx = N / 64;
    const int n0 = (wb % nbx) * 64;
    const int k0 = (wb / nbx) * 64;
#pragma unroll
    for (int it = 0; it < 4; ++it) {
        const int kl = it * 16 + (t >> 4);
        const int nl = (t & 15) * 4;
        *(float4*)&Ls[kl][nl] = *(const float4*)&Wm[(size_t)(k0 + kl) * N + n0 + nl];
    }
    __syncthreads();
#pragma unroll
    for (int it = 0; it < 4; ++it) {
        const int idx = it * 256 + t;
        const int nl  = idx & 63;
        const int ks  = (idx >> 6) * 4;
        short4v h, l;
#pragma unroll
        for (int j = 0; j < 4; ++j) {
            short th_, tl_;
            splitbf(Ls[ks + j][nl], th_, tl_);
            h[j] = th_; l[j] = tl_;
        }
        *(short4v*)&th[(size_t)(n0 + nl) * K + k0 + ks] = h;
        *(short4v*)&tl[(size_t)(n0 + nl) * K + k0 + ks] = l;
    }
}

// ---------------------------------------------------------------------------
// bf16-input x3 MFMA GEMM: C = A(MxK) @ Bt(NxK)^T, pre-split hi/lo operands.
// 128x128 tile, BK=32, 4 waves (2x2). Unchanged from round 7 (verified).
// ---------------------------------------------------------------------------
#define GKSTR 40

__global__ __launch_bounds__(256) void gemm_bf3(const short* __restrict__ Ah,
                                                const short* __restrict__ Al,
                                                const short* __restrict__ Bth,
                                                const short* __restrict__ Btl,
                                                short* __restrict__ Cm,
                                                int K, int N) {
    __shared__ __align__(16) short Ahs[128][GKSTR];
    __shared__ __align__(16) short Als[128][GKSTR];
    __shared__ __align__(16) short Bhs[128][GKSTR];
    __shared__ __align__(16) short Bls[128][GKSTR];

    const int t  = threadIdx.x;
    const int w  = t >> 6;
    const int lq = t & 15;
    const int hq = (t & 63) >> 4;
    const int wr = w >> 1;                 // wave row (m) 0..1
    const int wc = w & 1;                  // wave col (n) 0..1
    const int m0 = blockIdx.y * 128;
    const int n0 = blockIdx.x * 128;

    const int srow = t >> 1;
    const int scol = (t & 1) * 16;

    const short* gA_h = &Ah[(size_t)(m0 + srow) * K + scol];
    const short* gA_l = &Al[(size_t)(m0 + srow) * K + scol];
    const short* gB_h = &Bth[(size_t)(n0 + srow) * K + scol];
    const short* gB_l = &Btl[(size_t)(n0 + srow) * K + scol];

    f32x4 acc[4][4];
#pragma unroll
    for (int mi = 0; mi < 4; ++mi)
#pragma unroll
        for (int ni = 0; ni < 4; ++ni) acc[mi][ni] = (f32x4){0.f, 0.f, 0.f, 0.f};

    short8v ra_h0 = *(const short8v*)gA_h,       ra_h1 = *(const short8v*)(gA_h + 8);
    short8v ra_l0 = *(const short8v*)gA_l,       ra_l1 = *(const short8v*)(gA_l + 8);
    short8v rb_h0 = *(const short8v*)gB_h,       rb_h1 = *(const short8v*)(gB_h + 8);
    short8v rb_l0 = *(const short8v*)gB_l,       rb_l1 = *(const short8v*)(gB_l + 8);

    for (int k0 = 0; k0 < K; k0 += 32) {
        __syncthreads();
        *(short8v*)&Ahs[srow][scol]     = ra_h0;
        *(short8v*)&Ahs[srow][scol + 8] = ra_h1;
        *(short8v*)&Als[srow][scol]     = ra_l0;
        *(short8v*)&Als[srow][scol + 8] = ra_l1;
        *(short8v*)&Bhs[srow][scol]     = rb_h0;
        *(short8v*)&Bhs[srow][scol + 8] = rb_h1;
        *(short8v*)&Bls[srow][scol]     = rb_l0;
        *(short8v*)&Bls[srow][scol + 8] = rb_l1;
        __syncthreads();

        const int kn = k0 + 32;
        if (kn < K) {
            ra_h0 = *(const short8v*)(gA_h + kn); ra_h1 = *(const short8v*)(gA_h + kn + 8);
            ra_l0 = *(const short8v*)(gA_l + kn); ra_l1 = *(const short8v*)(gA_l + kn + 8);
            rb_h0 = *(const short8v*)(gB_h + kn); rb_h1 = *(const short8v*)(gB_h + kn + 8);
            rb_l0 = *(const short8v*)(gB_l + kn); rb_l1 = *(const short8v*)(gB_l + kn + 8);
        }

        short8v bnh[4], bnl[4];
#pragma unroll
        for (int ni = 0; ni < 4; ++ni) {
            bnh[ni] = *(const short8v*)&Bhs[wc * 64 + ni * 16 + lq][hq * 8];
            bnl[ni] = *(const short8v*)&Bls[wc * 64 + ni * 16 + lq][hq * 8];
        }
#pragma unroll
        for (int mi = 0; mi < 4; ++mi) {
            const short8v amh = *(const short8v*)&Ahs[wr * 64 + mi * 16 + lq][hq * 8];
            const short8v aml = *(const short8v*)&Als[wr * 64 + mi * 16 + lq][hq * 8];
#pragma unroll
            for (int ni = 0; ni < 4; ++ni) {
                acc[mi][ni] = __builtin_amdgcn_mfma_f32_16x16x32_bf16(amh, bnh[ni], acc[mi][ni], 0, 0, 0);
                acc[mi][ni] = __builtin_amdgcn_mfma_f32_16x16x32_bf16(amh, bnl[ni], acc[mi][ni], 0, 0, 0);
                acc[mi][ni] = __builtin_amdgcn_mfma_f32_16x16x32_bf16(aml, bnh[ni], acc[mi][ni], 0, 0, 0);
            }
        }
    }

#pragma unroll
    for (int mi = 0; mi < 4; ++mi)
#pragma unroll
        for (int ni = 0; ni < 4; ++ni) {
            const int col = n0 + wc * 64 + ni * 16 + lq;
#pragma unroll
            for (int r = 0; r < 4; ++r) {
                const int row = m0 + wr * 64 + mi * 16 + hq * 4 + r;
                Cm[(size_t)row * N + col] = f2bf(acc[mi][ni][r]);
            }
        }
}

// ---------------------------------------------------------------------------
// Transpose bf16 V (columns C..2C of kv_bf) into Vt_g[b][h][d][j].
// ---------------------------------------------------------------------------
__global__ __launch_bounds__(256) void v_transpose(const short* __restrict__ kv_bf,
                                                   short* __restrict__ vt) {
    __shared__ __align__(16) short Ls[128][72];
    const int t  = threadIdx.x;
    const int jt = blockIdx.x * 128;
    const int h  = blockIdx.y;
    const int b  = blockIdx.z;
    const short* src = kv_bf + (size_t)b * N_ * 2 * C_ + C_ + h * D_;
#pragma unroll
    for (int it = 0; it < 4; ++it) {
        const int idx = it * 256 + t;
        const int j = idx >> 3, d0 = (idx & 7) * 8;
        *(short8v*)&Ls[j][d0] = *(const short8v*)&src[(size_t)(jt + j) * (2 * C_) + d0];
    }
    __syncthreads();
    short* dst = vt + ((size_t)(b * H_ + h)) * D_ * N_;
#pragma unroll
    for (int it = 0; it < 4; ++it) {
        const int idx = it * 256 + t;
        const int d  = idx >> 4;           // 0..63
        const int j0 = (idx & 15) * 8;
        short8v s;
#pragma unroll
        for (int jj = 0; jj < 8; ++jj) s[jj] = Ls[j0 + jj][d];
        *(short8v*)&dst[(size_t)d * N_ + jt + j0] = s;
    }
}

// ---------------------------------------------------------------------------
// Two-pass MFMA attention, 32 q-rows per wave (block = 128 rows of one (b,h)).
// r7 structure (LDS-staged K/V, register-prefetched staging T14, XCD swizzle)
// -- reverted from r8's de-staged version (r8: latency-serialized, 2x slower;
// MfmaUtil 5%/VALU 17%/Occ 22%). One r8 lesson kept: Ps is wave-private
// (indexed by w), so the post-Ps __syncthreads is unnecessary -- r8 passed
// with identical absmax and no barrier there. Pass-2 barriers: 3 -> 2/tile.
// ---------------------------------------------------------------------------
#define KSTR 72
#define VSTR 136
#define PSTR 136

__global__ __launch_bounds__(256) void attn_mfma(const short* __restrict__ q,
                                                 const short* __restrict__ kv,
                                                 const short* __restrict__ vtg,
                                                 const int* __restrict__ mask,
                                                 float* __restrict__ out_att,
                                                 float* __restrict__ out_w) {
    __shared__ __align__(16) short Ks[128][KSTR];        // 18432 B
    __shared__ __align__(16) short Vt[64][VSTR];         // 17408 B
    __shared__ __align__(16) short Ps[4][32][PSTR];      // 34816 B (wave-private)
    __shared__ float linv_s[4][32];
    __shared__ int   mcol_s[128];

    const int t  = threadIdx.x;
    const int w  = t >> 6;
    const int l  = t & 63;
    const int lq = l & 15;
    const int hq = l >> 4;

    // XCD-aware bijective swizzle (512 blocks, 8 XCDs, 64 each = 4 panels)
    const int lin = blockIdx.x;
    const int swz = (lin & 7) * 64 + (lin >> 3);
    const int qb = swz & 15;            // 0..15
    const int h  = (swz >> 4) & 15;     // 0..15
    const int b  = swz >> 8;            // 0..1
    const int i0 = qb * 128 + w * 32;   // wave's first q row

    // staging decompositions (it-invariant parts)
    const int sj = t >> 3;              // K stage: row = it*32 + sj
    const int sd = (t & 7) * 8;         //          col = sd
    const int vd = t >> 4;              // V stage: row = it*16 + vd
    const int vj = (t & 15) * 8;        //          col = vj

    // ---- Q fragments, 2 row-groups: A[m=lq][k=kb*32+hq*8+e] ----
    short8v qa[2][2];
#pragma unroll
    for (int g = 0; g < 2; ++g) {
        const short* qrow = q + ((size_t)(b * N_ + i0 + g * 16 + lq)) * C_ + h * D_;
        qa[g][0] = *(const short8v*)&qrow[hq * 8];
        qa[g][1] = *(const short8v*)&qrow[32 + hq * 8];
    }

    int mr[2][4];
#pragma unroll
    for (int g = 0; g < 2; ++g)
#pragma unroll
        for (int r = 0; r < 4; ++r) mr[g][r] = mask[b * N_ + i0 + g * 16 + hq * 4 + r];

    const short* kbase = kv + (size_t)b * N_ * 2 * C_ + h * D_;
    const short* vtb   = vtg + ((size_t)(b * H_ + h)) * D_ * N_;

    // ---------------- pass 1: row sums only ----------------
    float lsum[2][4];
#pragma unroll
    for (int g = 0; g < 2; ++g)
#pragma unroll
        for (int r = 0; r < 4; ++r) lsum[g][r] = 0.f;

    short8v kr[4];
    int mpre = 0;
#pragma unroll
    for (int it = 0; it < 4; ++it)
        kr[it] = *(const short8v*)&kbase[(size_t)(it * 32 + sj) * (2 * C_) + sd];
    if (t < 128) mpre = mask[b * N_ + t];

    for (int tile = 0; tile < 16; ++tile) {
        __syncthreads();
#pragma unroll
        for (int it = 0; it < 4; ++it)
            *(short8v*)&Ks[it * 32 + sj][sd] = kr[it];
        if (t < 128) mcol_s[t] = mpre;
        __syncthreads();

        if (tile < 15) {
            const int jn = (tile + 1) * 128;
#pragma unroll
            for (int it = 0; it < 4; ++it)
                kr[it] = *(const short8v*)&kbase[(size_t)(jn + it * 32 + sj) * (2 * C_) + sd];
            if (t < 128) mpre = mask[b * N_ + jn + t];
        }

#pragma unroll
        for (int cb = 0; cb < 8; ++cb) {
            const short8v b0 = *(short8v*)&Ks[cb * 16 + lq][hq * 8];
            const short8v b1 = *(short8v*)&Ks[cb * 16 + lq][32 + hq * 8];
            const int mc = mcol_s[cb * 16 + lq];
#pragma unroll
            for (int g = 0; g < 2; ++g) {
                f32x4 acc = {0.f, 0.f, 0.f, 0.f};
                acc = __builtin_amdgcn_mfma_f32_16x16x32_bf16(qa[g][0], b0, acc, 0, 0, 0);
                acc = __builtin_amdgcn_mfma_f32_16x16x32_bf16(qa[g][1], b1, acc, 0, 0, 0);
#pragma unroll
                for (int r = 0; r < 4; ++r)
                    lsum[g][r] += mr[g][r] ? 1.0f : (mc ? 0.0f : __expf(acc[r] * 0.125f));
            }
        }
    }
    float inv[2][4];
#pragma unroll
    for (int g = 0; g < 2; ++g)
#pragma unroll
        for (int r = 0; r < 4; ++r) {
            float s = lsum[g][r];
#pragma unroll
            for (int off = 1; off < 16; off <<= 1) s += __shfl_xor(s, off, 64);
            inv[g][r] = 1.0f / s;
        }
    if (lq == 0)
#pragma unroll
        for (int g = 0; g < 2; ++g)
#pragma unroll
            for (int r = 0; r < 4; ++r) linv_s[w][g * 16 + hq * 4 + r] = inv[g][r];

    float* wbase[2];
#pragma unroll
    for (int g = 0; g < 2; ++g)
        wbase[g] = out_w + ((size_t)((b * H_ + h) * N_ + i0 + g * 16 + hq * 4)) * N_;

    f32x4 oacc[4][2];
#pragma unroll
    for (int db = 0; db < 4; ++db)
#pragma unroll
        for (int g = 0; g < 2; ++g) oacc[db][g] = (f32x4){0.f, 0.f, 0.f, 0.f};

    // ---------------- pass 2 ----------------
    short8v vr[4];
#pragma unroll
    for (int it = 0; it < 4; ++it) {
        kr[it] = *(const short8v*)&kbase[(size_t)(it * 32 + sj) * (2 * C_) + sd];
        vr[it] = *(const short8v*)&vtb[(size_t)(it * 16 + vd) * N_ + vj];
    }
    if (t < 128) mpre = mask[b * N_ + t];

    for (int tile = 0; tile < 16; ++tile) {
        const int jt = tile * 128;
        __syncthreads();
#pragma unroll
        for (int it = 0; it < 4; ++it) {
            *(short8v*)&Ks[it * 32 + sj][sd] = kr[it];
            *(short8v*)&Vt[it * 16 + vd][vj] = vr[it];
        }
        if (t < 128) mcol_s[t] = mpre;
        __syncthreads();

        if (tile < 15) {
            const int jn = jt + 128;
#pragma unroll
            for (int it = 0; it < 4; ++it) {
                kr[it] = *(const short8v*)&kbase[(size_t)(jn + it * 32 + sj) * (2 * C_) + sd];
                vr[it] = *(const short8v*)&vtb[(size_t)(it * 16 + vd) * N_ + jn + vj];
            }
            if (t < 128) mpre = mask[b * N_ + jn + t];
        }

#pragma unroll
        for (int cb = 0; cb < 8; ++cb) {
            const short8v b0 = *(short8v*)&Ks[cb * 16 + lq][hq * 8];
            const short8v b1 = *(short8v*)&Ks[cb * 16 + lq][32 + hq * 8];
            const int mc   = mcol_s[cb * 16 + lq];
            const int jcol = cb * 16 + lq;
#pragma unroll
            for (int g = 0; g < 2; ++g) {
                f32x4 acc = {0.f, 0.f, 0.f, 0.f};
                acc = __builtin_amdgcn_mfma_f32_16x16x32_bf16(qa[g][0], b0, acc, 0, 0, 0);
                acc = __builtin_amdgcn_mfma_f32_16x16x32_bf16(qa[g][1], b1, acc, 0, 0, 0);
#pragma unroll
                for (int r = 0; r < 4; ++r) {
                    const float ev = mr[g][r] ? 1.0f : (mc ? 0.0f : __expf(acc[r] * 0.125f));
                    wbase[g][(size_t)r * N_ + jt + jcol] = ev * inv[g][r];   // normalized weight
                    Ps[w][g * 16 + hq * 4 + r][jcol] = f2bf(ev);
                }
            }
        }
        // NO barrier here: Ps[w] is wave-private; intra-wave lgkmcnt ordering
        // suffices (validated by r8's barrier-free kernel, identical absmax).

        // att^T += V^T @ P  (pb hoisted: db-invariant)
        short8v pb[2][4];
#pragma unroll
        for (int kb = 0; kb < 4; ++kb) {
            pb[0][kb] = *(short8v*)&Ps[w][lq][kb * 32 + hq * 8];
            pb[1][kb] = *(short8v*)&Ps[w][16 + lq][kb * 32 + hq * 8];
        }
#pragma unroll
        for (int db = 0; db < 4; ++db)
#pragma unroll
            for (int kb = 0; kb < 4; ++kb) {
                const short8v va = *(short8v*)&Vt[db * 16 + lq][kb * 32 + hq * 8];
                oacc[db][0] = __builtin_amdgcn_mfma_f32_16x16x32_bf16(va, pb[0][kb], oacc[db][0], 0, 0, 0);
                oacc[db][1] = __builtin_amdgcn_mfma_f32_16x16x32_bf16(va, pb[1][kb], oacc[db][1], 0, 0, 0);
            }
    }

    // ---- att: scale accumulators, scalar stores (row=g*16+lq, d=db*16+hq*4+r) ----
#pragma unroll
    for (int g = 0; g < 2; ++g) {
        const float invi = linv_s[w][g * 16 + lq];
        const size_t abase = ((size_t)(b * N_ + i0 + g * 16 + lq)) * C_ + h * D_;
#pragma unroll
        for (int db = 0; db < 4; ++db)
#pragma unroll
            for (int r = 0; r < 4; ++r)
                out_att[abase + db * 16 + hq * 4 + r] = oacc[db][g][r] * invi;
    }
}

// ---------------------------------------------------------------------------
// Workspace layout (shorts), total 24M shorts = 48 MB:
//   qbf  [0,  4M)   q bf16
//   kvbf [4M, 12M)  kv bf16
//   Ah   [12M,16M)  A-split hi (reused); vt overlays after gemms
//   Al   [16M,20M)  A-split lo
//   Wth  [20M,22M)  W^T hi
//   Wtl  [22M,24M)  W^T lo
// ---------------------------------------------------------------------------
extern "C" void kernel_launch(void* const* d_in, const int* in_sizes, int n_in,
                              void* d_out, int out_size, void* d_ws, size_t ws_size,
                              hipStream_t stream) {
    const float* hs   = (const float*)d_in[0];
    const float* ehs  = (const float*)d_in[1];
    const int*   mask = (const int*)d_in[2];
    const float* W_q  = (const float*)d_in[3];
    const float* W_c  = (const float*)d_in[4];

    float* out_att = (float*)d_out;
    float* out_w   = (float*)d_out + (size_t)B_ * N_ * C_;

    const size_t M1 = (size_t)1024 * 1024;
    short* qbf  = (short*)d_ws;
    short* kvbf = qbf + 4 * M1;
    short* Ah   = kvbf + 8 * M1;
    short* Al   = Ah + 4 * M1;
    short* vt   = Ah;                       // overlay: used only after gemms
    short* Wth  = Al + 4 * M1;
    short* Wtl  = Wth + 2 * M1;

    const int nAblk = (B_ * N_ * C_) / 1024;   // 4096

    // ---- q = hs @ W_q ----
    split_aw<<<dim3(nAblk + (C_ / 64) * (C_ / 64)), 256, 0, stream>>>(
        hs, Ah, Al, nAblk, W_q, Wth, Wtl, C_, C_);
    gemm_bf3<<<dim3(C_ / 128, (B_ * N_) / 128), 256, 0, stream>>>(
        Ah, Al, Wth, Wtl, qbf, C_, C_);

    // ---- kv = ehs @ W_c ----
    split_aw<<<dim3(nAblk + ((2 * C_) / 64) * (C_ / 64)), 256, 0, stream>>>(
        ehs, Ah, Al, nAblk, W_c, Wth, Wtl, C_, 2 * C_);
    gemm_bf3<<<dim3((2 * C_) / 128, (B_ * N_) / 128), 256, 0, stream>>>(
        Ah, Al, Wth, Wtl, kvbf, C_, 2 * C_);

    // ---- V transpose + attention ----
    v_transpose<<<dim3(N_ / 128, H_, B_), 256, 0, stream>>>(kvbf, vt);
    attn_mfma<<<dim3(512), 256, 0, stream>>>(
        qbf, kvbf, vt, mask, out_att, out_w);
}

// Round 10
// 323.395 us; speedup vs baseline: 1.6199x; 1.0173x over previous
//
#include <hip/hip_runtime.h>
#include <math.h>

#define B_ 2
#define N_ 2048
#define C_ 1024
#define H_ 16
#define D_ 64

typedef __attribute__((ext_vector_type(8))) short short8v;
typedef __attribute__((ext_vector_type(4))) short short4v;
typedef __attribute__((ext_vector_type(4))) float f32x4;

static __device__ __forceinline__ short f2bf(float f) {
    union { float f; unsigned u; } v; v.f = f;
    unsigned r = v.u + 0x7FFFu + ((v.u >> 16) & 1u);   // RNE
    return (short)(r >> 16);
}

// Split fp32 into hi/lo truncated bf16: f = hi + lo + O(2^-16 * f).
// a*b ~= ah*bh + ah*bl + al*bh  (dropped al*bl ~ 2^-16 rel) -> fp32-grade GEMM.
static __device__ __forceinline__ void splitbf(float f, short& h, short& l) {
    union { float f; unsigned u; } v; v.f = f;
    const unsigned uh = v.u & 0xFFFF0000u;
    h = (short)(uh >> 16);
    union { unsigned u; float f; } w; w.u = uh;
    union { float f; unsigned u; } x; x.f = f - w.f;   // exact (Sterbenz)
    l = (short)(x.u >> 16);
}

// LDS-only barrier: lgkmcnt(0) + raw s_barrier, WITHOUT the compiler's
// vmcnt(0) drain that __syncthreads() emits. Outstanding global STORES stay
// in flight across phases (nothing reads them in-kernel), so the out_w
// store stream overlaps with the next phase's compute instead of
// serializing at every barrier. sched_barrier(0) on both sides pins
// program order (guide rule #18: hipcc can hoist past inline-asm waitcnt).
static __device__ __forceinline__ void lds_barrier() {
    __builtin_amdgcn_sched_barrier(0);
    asm volatile("s_waitcnt lgkmcnt(0)" ::: "memory");
    __builtin_amdgcn_s_barrier();
    __builtin_amdgcn_sched_barrier(0);
}

// ---------------------------------------------------------------------------
// split_aw: fused {elementwise A-split} + {W transpose-split}. Unchanged (r9).
// ---------------------------------------------------------------------------
__global__ __launch_bounds__(256) void split_aw(const float* __restrict__ src,
                                                short* __restrict__ hi,
                                                short* __restrict__ lo,
                                                int nA,
                                                const float* __restrict__ Wm,
                                                short* __restrict__ th,
                                                short* __restrict__ tl,
                                                int K, int N) {
    __shared__ float Ls[64][68];
    const int t = threadIdx.x;
    if ((int)blockIdx.x < nA) {
        const int i = (blockIdx.x * 256 + t) * 4;
        const float4 f = *(const float4*)&src[i];
        short4v h, l;
        short th_, tl_;
        splitbf(f.x, th_, tl_); h[0] = th_; l[0] = tl_;
        splitbf(f.y, th_, tl_); h[1] = th_; l[1] = tl_;
        splitbf(f.z, th_, tl_); h[2] = th_; l[2] = tl_;
        splitbf(f.w, th_, tl_); h[3] = th_; l[3] = tl_;
        *(short4v*)&hi[i] = h;
        *(short4v*)&lo[i] = l;
        return;
    }
    const int wb  = blockIdx.x - nA;
    const int nbx = N / 64;
    const int n0 = (wb % nbx) * 64;
    const int k0 = (wb / nbx) * 64;
#pragma unroll
    for (int it = 0; it < 4; ++it) {
        const int kl = it * 16 + (t >> 4);
        const int nl = (t & 15) * 4;
        *(float4*)&Ls[kl][nl] = *(const float4*)&Wm[(size_t)(k0 + kl) * N + n0 + nl];
    }
    __syncthreads();
#pragma unroll
    for (int it = 0; it < 4; ++it) {
        const int idx = it * 256 + t;
        const int nl  = idx & 63;
        const int ks  = (idx >> 6) * 4;
        short4v h, l;
#pragma unroll
        for (int j = 0; j < 4; ++j) {
            short th_, tl_;
            splitbf(Ls[ks + j][nl], th_, tl_);
            h[j] = th_; l[j] = tl_;
        }
        *(short4v*)&th[(size_t)(n0 + nl) * K + k0 + ks] = h;
        *(short4v*)&tl[(size_t)(n0 + nl) * K + k0 + ks] = l;
    }
}

// ---------------------------------------------------------------------------
// bf16-input x3 MFMA GEMM. Unchanged (r7-verified).
// ---------------------------------------------------------------------------
#define GKSTR 40

__global__ __launch_bounds__(256) void gemm_bf3(const short* __restrict__ Ah,
                                                const short* __restrict__ Al,
                                                const short* __restrict__ Bth,
                                                const short* __restrict__ Btl,
                                                short* __restrict__ Cm,
                                                int K, int N) {
    __shared__ __align__(16) short Ahs[128][GKSTR];
    __shared__ __align__(16) short Als[128][GKSTR];
    __shared__ __align__(16) short Bhs[128][GKSTR];
    __shared__ __align__(16) short Bls[128][GKSTR];

    const int t  = threadIdx.x;
    const int w  = t >> 6;
    const int lq = t & 15;
    const int hq = (t & 63) >> 4;
    const int wr = w >> 1;
    const int wc = w & 1;
    const int m0 = blockIdx.y * 128;
    const int n0 = blockIdx.x * 128;

    const int srow = t >> 1;
    const int scol = (t & 1) * 16;

    const short* gA_h = &Ah[(size_t)(m0 + srow) * K + scol];
    const short* gA_l = &Al[(size_t)(m0 + srow) * K + scol];
    const short* gB_h = &Bth[(size_t)(n0 + srow) * K + scol];
    const short* gB_l = &Btl[(size_t)(n0 + srow) * K + scol];

    f32x4 acc[4][4];
#pragma unroll
    for (int mi = 0; mi < 4; ++mi)
#pragma unroll
        for (int ni = 0; ni < 4; ++ni) acc[mi][ni] = (f32x4){0.f, 0.f, 0.f, 0.f};

    short8v ra_h0 = *(const short8v*)gA_h,       ra_h1 = *(const short8v*)(gA_h + 8);
    short8v ra_l0 = *(const short8v*)gA_l,       ra_l1 = *(const short8v*)(gA_l + 8);
    short8v rb_h0 = *(const short8v*)gB_h,       rb_h1 = *(const short8v*)(gB_h + 8);
    short8v rb_l0 = *(const short8v*)gB_l,       rb_l1 = *(const short8v*)(gB_l + 8);

    for (int k0 = 0; k0 < K; k0 += 32) {
        __syncthreads();
        *(short8v*)&Ahs[srow][scol]     = ra_h0;
        *(short8v*)&Ahs[srow][scol + 8] = ra_h1;
        *(short8v*)&Als[srow][scol]     = ra_l0;
        *(short8v*)&Als[srow][scol + 8] = ra_l1;
        *(short8v*)&Bhs[srow][scol]     = rb_h0;
        *(short8v*)&Bhs[srow][scol + 8] = rb_h1;
        *(short8v*)&Bls[srow][scol]     = rb_l0;
        *(short8v*)&Bls[srow][scol + 8] = rb_l1;
        __syncthreads();

        const int kn = k0 + 32;
        if (kn < K) {
            ra_h0 = *(const short8v*)(gA_h + kn); ra_h1 = *(const short8v*)(gA_h + kn + 8);
            ra_l0 = *(const short8v*)(gA_l + kn); ra_l1 = *(const short8v*)(gA_l + kn + 8);
            rb_h0 = *(const short8v*)(gB_h + kn); rb_h1 = *(const short8v*)(gB_h + kn + 8);
            rb_l0 = *(const short8v*)(gB_l + kn); rb_l1 = *(const short8v*)(gB_l + kn + 8);
        }

        short8v bnh[4], bnl[4];
#pragma unroll
        for (int ni = 0; ni < 4; ++ni) {
            bnh[ni] = *(const short8v*)&Bhs[wc * 64 + ni * 16 + lq][hq * 8];
            bnl[ni] = *(const short8v*)&Bls[wc * 64 + ni * 16 + lq][hq * 8];
        }
#pragma unroll
        for (int mi = 0; mi < 4; ++mi) {
            const short8v amh = *(const short8v*)&Ahs[wr * 64 + mi * 16 + lq][hq * 8];
            const short8v aml = *(const short8v*)&Als[wr * 64 + mi * 16 + lq][hq * 8];
#pragma unroll
            for (int ni = 0; ni < 4; ++ni) {
                acc[mi][ni] = __builtin_amdgcn_mfma_f32_16x16x32_bf16(amh, bnh[ni], acc[mi][ni], 0, 0, 0);
                acc[mi][ni] = __builtin_amdgcn_mfma_f32_16x16x32_bf16(amh, bnl[ni], acc[mi][ni], 0, 0, 0);
                acc[mi][ni] = __builtin_amdgcn_mfma_f32_16x16x32_bf16(aml, bnh[ni], acc[mi][ni], 0, 0, 0);
            }
        }
    }

#pragma unroll
    for (int mi = 0; mi < 4; ++mi)
#pragma unroll
        for (int ni = 0; ni < 4; ++ni) {
            const int col = n0 + wc * 64 + ni * 16 + lq;
#pragma unroll
            for (int r = 0; r < 4; ++r) {
                const int row = m0 + wr * 64 + mi * 16 + hq * 4 + r;
                Cm[(size_t)row * N + col] = f2bf(acc[mi][ni][r]);
            }
        }
}

// ---------------------------------------------------------------------------
// Transpose bf16 V (columns C..2C of kv_bf) into Vt_g[b][h][d][j]. Unchanged.
// ---------------------------------------------------------------------------
__global__ __launch_bounds__(256) void v_transpose(const short* __restrict__ kv_bf,
                                                   short* __restrict__ vt) {
    __shared__ __align__(16) short Ls[128][72];
    const int t  = threadIdx.x;
    const int jt = blockIdx.x * 128;
    const int h  = blockIdx.y;
    const int b  = blockIdx.z;
    const short* src = kv_bf + (size_t)b * N_ * 2 * C_ + C_ + h * D_;
#pragma unroll
    for (int it = 0; it < 4; ++it) {
        const int idx = it * 256 + t;
        const int j = idx >> 3, d0 = (idx & 7) * 8;
        *(short8v*)&Ls[j][d0] = *(const short8v*)&src[(size_t)(jt + j) * (2 * C_) + d0];
    }
    __syncthreads();
    short* dst = vt + ((size_t)(b * H_ + h)) * D_ * N_;
#pragma unroll
    for (int it = 0; it < 4; ++it) {
        const int idx = it * 256 + t;
        const int d  = idx >> 4;           // 0..63
        const int j0 = (idx & 15) * 8;
        short8v s;
#pragma unroll
        for (int jj = 0; jj < 8; ++jj) s[jj] = Ls[j0 + jj][d];
        *(short8v*)&dst[(size_t)d * N_ + jt + j0] = s;
    }
}

// ---------------------------------------------------------------------------
// Two-pass MFMA attention (r7 structure) with lds_barrier() instead of
// __syncthreads(): the compiler's vmcnt(0)-drain-at-barrier forced ~64KB of
// out_w stores per block to COMPLETE inside every pass-2 phase (store BW
// strictly serialized with compute). lds_barrier keeps only the lgkmcnt(0)
// LDS fence; w-stores stay in flight across phases and drain under the next
// phase's MFMA/exp. Math/order untouched -> bit-identical output.
// ---------------------------------------------------------------------------
#define KSTR 72
#define VSTR 136
#define PSTR 136

__global__ __launch_bounds__(256) void attn_mfma(const short* __restrict__ q,
                                                 const short* __restrict__ kv,
                                                 const short* __restrict__ vtg,
                                                 const int* __restrict__ mask,
                                                 float* __restrict__ out_att,
                                                 float* __restrict__ out_w) {
    __shared__ __align__(16) short Ks[128][KSTR];        // 18432 B
    __shared__ __align__(16) short Vt[64][VSTR];         // 17408 B
    __shared__ __align__(16) short Ps[4][32][PSTR];      // 34816 B (wave-private)
    __shared__ float linv_s[4][32];
    __shared__ int   mcol_s[128];

    const int t  = threadIdx.x;
    const int w  = t >> 6;
    const int l  = t & 63;
    const int lq = l & 15;
    const int hq = l >> 4;

    // XCD-aware bijective swizzle (512 blocks, 8 XCDs, 64 each = 4 panels)
    const int lin = blockIdx.x;
    const int swz = (lin & 7) * 64 + (lin >> 3);
    const int qb = swz & 15;            // 0..15
    const int h  = (swz >> 4) & 15;     // 0..15
    const int b  = swz >> 8;            // 0..1
    const int i0 = qb * 128 + w * 32;   // wave's first q row

    // staging decompositions (it-invariant parts)
    const int sj = t >> 3;              // K stage: row = it*32 + sj
    const int sd = (t & 7) * 8;         //          col = sd
    const int vd = t >> 4;              // V stage: row = it*16 + vd
    const int vj = (t & 15) * 8;        //          col = vj

    // ---- Q fragments, 2 row-groups: A[m=lq][k=kb*32+hq*8+e] ----
    short8v qa[2][2];
#pragma unroll
    for (int g = 0; g < 2; ++g) {
        const short* qrow = q + ((size_t)(b * N_ + i0 + g * 16 + lq)) * C_ + h * D_;
        qa[g][0] = *(const short8v*)&qrow[hq * 8];
        qa[g][1] = *(const short8v*)&qrow[32 + hq * 8];
    }

    int mr[2][4];
#pragma unroll
    for (int g = 0; g < 2; ++g)
#pragma unroll
        for (int r = 0; r < 4; ++r) mr[g][r] = mask[b * N_ + i0 + g * 16 + hq * 4 + r];

    const short* kbase = kv + (size_t)b * N_ * 2 * C_ + h * D_;
    const short* vtb   = vtg + ((size_t)(b * H_ + h)) * D_ * N_;

    // ---------------- pass 1: row sums only ----------------
    float lsum[2][4];
#pragma unroll
    for (int g = 0; g < 2; ++g)
#pragma unroll
        for (int r = 0; r < 4; ++r) lsum[g][r] = 0.f;

    short8v kr[4];
    int mpre = 0;
#pragma unroll
    for (int it = 0; it < 4; ++it)
        kr[it] = *(const short8v*)&kbase[(size_t)(it * 32 + sj) * (2 * C_) + sd];
    if (t < 128) mpre = mask[b * N_ + t];

    for (int tile = 0; tile < 16; ++tile) {
        lds_barrier();
#pragma unroll
        for (int it = 0; it < 4; ++it)
            *(short8v*)&Ks[it * 32 + sj][sd] = kr[it];
        if (t < 128) mcol_s[t] = mpre;
        lds_barrier();

        if (tile < 15) {
            const int jn = (tile + 1) * 128;
#pragma unroll
            for (int it = 0; it < 4; ++it)
                kr[it] = *(const short8v*)&kbase[(size_t)(jn + it * 32 + sj) * (2 * C_) + sd];
            if (t < 128) mpre = mask[b * N_ + jn + t];
        }

#pragma unroll
        for (int cb = 0; cb < 8; ++cb) {
            const short8v b0 = *(short8v*)&Ks[cb * 16 + lq][hq * 8];
            const short8v b1 = *(short8v*)&Ks[cb * 16 + lq][32 + hq * 8];
            const int mc = mcol_s[cb * 16 + lq];
#pragma unroll
            for (int g = 0; g < 2; ++g) {
                f32x4 acc = {0.f, 0.f, 0.f, 0.f};
                acc = __builtin_amdgcn_mfma_f32_16x16x32_bf16(qa[g][0], b0, acc, 0, 0, 0);
                acc = __builtin_amdgcn_mfma_f32_16x16x32_bf16(qa[g][1], b1, acc, 0, 0, 0);
#pragma unroll
                for (int r = 0; r < 4; ++r)
                    lsum[g][r] += mr[g][r] ? 1.0f : (mc ? 0.0f : __expf(acc[r] * 0.125f));
            }
        }
    }
    float inv[2][4];
#pragma unroll
    for (int g = 0; g < 2; ++g)
#pragma unroll
        for (int r = 0; r < 4; ++r) {
            float s = lsum[g][r];
#pragma unroll
            for (int off = 1; off < 16; off <<= 1) s += __shfl_xor(s, off, 64);
            inv[g][r] = 1.0f / s;
        }
    if (lq == 0)
#pragma unroll
        for (int g = 0; g < 2; ++g)
#pragma unroll
            for (int r = 0; r < 4; ++r) linv_s[w][g * 16 + hq * 4 + r] = inv[g][r];

    float* wbase[2];
#pragma unroll
    for (int g = 0; g < 2; ++g)
        wbase[g] = out_w + ((size_t)((b * H_ + h) * N_ + i0 + g * 16 + hq * 4)) * N_;

    f32x4 oacc[4][2];
#pragma unroll
    for (int db = 0; db < 4; ++db)
#pragma unroll
        for (int g = 0; g < 2; ++g) oacc[db][g] = (f32x4){0.f, 0.f, 0.f, 0.f};

    // ---------------- pass 2 ----------------
    short8v vr[4];
#pragma unroll
    for (int it = 0; it < 4; ++it) {
        kr[it] = *(const short8v*)&kbase[(size_t)(it * 32 + sj) * (2 * C_) + sd];
        vr[it] = *(const short8v*)&vtb[(size_t)(it * 16 + vd) * N_ + vj];
    }
    if (t < 128) mpre = mask[b * N_ + t];

    for (int tile = 0; tile < 16; ++tile) {
        const int jt = tile * 128;
        lds_barrier();
#pragma unroll
        for (int it = 0; it < 4; ++it) {
            *(short8v*)&Ks[it * 32 + sj][sd] = kr[it];
            *(short8v*)&Vt[it * 16 + vd][vj] = vr[it];
        }
        if (t < 128) mcol_s[t] = mpre;
        lds_barrier();

        if (tile < 15) {
            const int jn = jt + 128;
#pragma unroll
            for (int it = 0; it < 4; ++it) {
                kr[it] = *(const short8v*)&kbase[(size_t)(jn + it * 32 + sj) * (2 * C_) + sd];
                vr[it] = *(const short8v*)&vtb[(size_t)(it * 16 + vd) * N_ + jn + vj];
            }
            if (t < 128) mpre = mask[b * N_ + jn + t];
        }

#pragma unroll
        for (int cb = 0; cb < 8; ++cb) {
            const short8v b0 = *(short8v*)&Ks[cb * 16 + lq][hq * 8];
            const short8v b1 = *(short8v*)&Ks[cb * 16 + lq][32 + hq * 8];
            const int mc   = mcol_s[cb * 16 + lq];
            const int jcol = cb * 16 + lq;
#pragma unroll
            for (int g = 0; g < 2; ++g) {
                f32x4 acc = {0.f, 0.f, 0.f, 0.f};
                acc = __builtin_amdgcn_mfma_f32_16x16x32_bf16(qa[g][0], b0, acc, 0, 0, 0);
                acc = __builtin_amdgcn_mfma_f32_16x16x32_bf16(qa[g][1], b1, acc, 0, 0, 0);
#pragma unroll
                for (int r = 0; r < 4; ++r) {
                    const float ev = mr[g][r] ? 1.0f : (mc ? 0.0f : __expf(acc[r] * 0.125f));
                    wbase[g][(size_t)r * N_ + jt + jcol] = ev * inv[g][r];   // normalized weight
                    Ps[w][g * 16 + hq * 4 + r][jcol] = f2bf(ev);
                }
            }
        }
        // NO barrier here: Ps[w] is wave-private (validated r8).

        // att^T += V^T @ P  (pb hoisted: db-invariant)
        short8v pb[2][4];
#pragma unroll
        for (int kb = 0; kb < 4; ++kb) {
            pb[0][kb] = *(short8v*)&Ps[w][lq][kb * 32 + hq * 8];
            pb[1][kb] = *(short8v*)&Ps[w][16 + lq][kb * 32 + hq * 8];
        }
#pragma unroll
        for (int db = 0; db < 4; ++db)
#pragma unroll
            for (int kb = 0; kb < 4; ++kb) {
                const short8v va = *(short8v*)&Vt[db * 16 + lq][kb * 32 + hq * 8];
                oacc[db][0] = __builtin_amdgcn_mfma_f32_16x16x32_bf16(va, pb[0][kb], oacc[db][0], 0, 0, 0);
                oacc[db][1] = __builtin_amdgcn_mfma_f32_16x16x32_bf16(va, pb[1][kb], oacc[db][1], 0, 0, 0);
            }
    }

    // ---- att: scale accumulators, scalar stores (row=g*16+lq, d=db*16+hq*4+r) ----
#pragma unroll
    for (int g = 0; g < 2; ++g) {
        const float invi = linv_s[w][g * 16 + lq];
        const size_t abase = ((size_t)(b * N_ + i0 + g * 16 + lq)) * C_ + h * D_;
#pragma unroll
        for (int db = 0; db < 4; ++db)
#pragma unroll
            for (int r = 0; r < 4; ++r)
                out_att[abase + db * 16 + hq * 4 + r] = oacc[db][g][r] * invi;
    }
}

// ---------------------------------------------------------------------------
// Workspace layout (shorts), total 24M shorts = 48 MB:
//   qbf  [0,  4M)   q bf16
//   kvbf [4M, 12M)  kv bf16
//   Ah   [12M,16M)  A-split hi (reused); vt overlays after gemms
//   Al   [16M,20M)  A-split lo
//   Wth  [20M,22M)  W^T hi
//   Wtl  [22M,24M)  W^T lo
// ---------------------------------------------------------------------------
extern "C" void kernel_launch(void* const* d_in, const int* in_sizes, int n_in,
                              void* d_out, int out_size, void* d_ws, size_t ws_size,
                              hipStream_t stream) {
    const float* hs   = (const float*)d_in[0];
    const float* ehs  = (const float*)d_in[1];
    const int*   mask = (const int*)d_in[2];
    const float* W_q  = (const float*)d_in[3];
    const float* W_c  = (const float*)d_in[4];

    float* out_att = (float*)d_out;
    float* out_w   = (float*)d_out + (size_t)B_ * N_ * C_;

    const size_t M1 = (size_t)1024 * 1024;
    short* qbf  = (short*)d_ws;
    short* kvbf = qbf + 4 * M1;
    short* Ah   = kvbf + 8 * M1;
    short* Al   = Ah + 4 * M1;
    short* vt   = Ah;                       // overlay: used only after gemms
    short* Wth  = Al + 4 * M1;
    short* Wtl  = Wth + 2 * M1;

    const int nAblk = (B_ * N_ * C_) / 1024;   // 4096

    // ---- q = hs @ W_q ----
    split_aw<<<dim3(nAblk + (C_ / 64) * (C_ / 64)), 256, 0, stream>>>(
        hs, Ah, Al, nAblk, W_q, Wth, Wtl, C_, C_);
    gemm_bf3<<<dim3(C_ / 128, (B_ * N_) / 128), 256, 0, stream>>>(
        Ah, Al, Wth, Wtl, qbf, C_, C_);

    // ---- kv = ehs @ W_c ----
    split_aw<<<dim3(nAblk + ((2 * C_) / 64) * (C_ / 64)), 256, 0, stream>>>(
        ehs, Ah, Al, nAblk, W_c, Wth, Wtl, C_, 2 * C_);
    gemm_bf3<<<dim3((2 * C_) / 128, (B_ * N_) / 128), 256, 0, stream>>>(
        Ah, Al, Wth, Wtl, kvbf, C_, 2 * C_);

    // ---- V transpose + attention ----
    v_transpose<<<dim3(N_ / 128, H_, B_), 256, 0, stream>>>(kvbf, vt);
    attn_mfma<<<dim3(512), 256, 0, stream>>>(
        qbf, kvbf, vt, mask, out_att, out_w);
}